// Round 2
// baseline (1156.519 us; speedup 1.0000x reference)
//
#include <hip/hip_runtime.h>
#include <hip/hip_bf16.h>

// Pipeline (channel-major [B,512,N=1024] throughout, matching in/out layout):
//   Qt[b] = Wq^T @ X[b]   (same Kt, Vt)            [B,512,1024] bf16 (ws)
//   softmax over contiguous n-axis on Kt rows (in place)
//   ctx[b,h] = Ksm_bh (64x1024) @ Vt_bh^T          [B,8,64,64] fp32 (ws)
//   Weff[b][h*64+d][c] = sum_v ctx[b,h,d,v]*Wp[h*64+v,c]   [B,512,512] bf16
//   out[b] = Weff[b] @ Qt[b] + bp                  -> d_out
// Folding q@ctx and @Wp into Weff saves a full 512x1024x512 GEMM pass.
//
// DTYPE AMBIGUITY: reference declares fp32, harness label hints bf16. A probe
// kernel detects which at runtime (flag in ws: 1=bf16, 0=fp32); all loads of
// original inputs and the final store branch on it (wave-uniform, ~free).

__device__ __forceinline__ float bf2f(unsigned short u) {
    union { unsigned int i; float f; } x;
    x.i = ((unsigned int)u) << 16;
    return x.f;
}

__device__ __forceinline__ unsigned short f2bf(float f) {
    unsigned int u = __float_as_uint(f);
    unsigned int lsb = (u >> 16) & 1u;
    u += 0x7fffu + lsb;             // round-to-nearest-even
    return (unsigned short)(u >> 16);
}

__device__ __forceinline__ float waveReduceMax(float v) {
    #pragma unroll
    for (int off = 32; off > 0; off >>= 1) v = fmaxf(v, __shfl_xor(v, off, 64));
    return v;
}
__device__ __forceinline__ float waveReduceSum(float v) {
    #pragma unroll
    for (int off = 32; off > 0; off >>= 1) v += __shfl_xor(v, off, 64);
    return v;
}

// Detect input dtype. Even-index ushorts of fp32 data are low mantissa bits
// (exponent-field uniform random -> ~12% "sane"); of bf16 N(0,1) data they
// are real values (>99% sane). flag: 1 = bf16, 0 = fp32.
__global__ void detect_dtype(const unsigned short* __restrict__ x, int* __restrict__ flag)
{
    int t = threadIdx.x;                      // 64 threads
    unsigned short u = x[2 * t];
    int e = (u >> 7) & 0xFF;
    int sane = (e >= 113 && e <= 142) ? 1 : 0;
    #pragma unroll
    for (int off = 32; off > 0; off >>= 1) sane += __shfl_xor(sane, off, 64);
    if (t == 0) *flag = (sane >= 32) ? 1 : 0;
}

__device__ __forceinline__ void load4(const void* p, long idx, bool asf32, float o[4]) {
    if (asf32) {
        float4 v = *(const float4*)((const float*)p + idx);
        o[0] = v.x; o[1] = v.y; o[2] = v.z; o[3] = v.w;
    } else {
        ushort4 v = *(const ushort4*)((const unsigned short*)p + idx);
        o[0] = bf2f(v.x); o[1] = bf2f(v.y); o[2] = bf2f(v.z); o[3] = bf2f(v.w);
    }
}

// C[b,m,n] = sum_k A[k,m] * X[b,k,n] (+ bias[m])
// in_dyn:  A,X are original inputs -> dtype per flag (else fixed bf16)
// out_dyn: C is d_out, bias is original input -> dtype per flag (else bf16)
// Tile: 64x64 per block, 4x4 per thread, BK=16, fp32 accumulate.
__global__ __launch_bounds__(256) void gemm_wt_x(
    const void* __restrict__ A, long a_bstride,
    const void* __restrict__ X,
    const void* __restrict__ bias,
    void* __restrict__ C,
    int M, int N, int K,
    const int* __restrict__ flag, int in_dyn, int out_dyn)
{
    const int fl = *flag;                    // wave-uniform scalar load
    const bool f32in = (in_dyn  != 0) && (fl == 0);
    const bool f32io = (out_dyn != 0) && (fl == 0);

    const int b  = blockIdx.z;
    const int n0 = blockIdx.x * 64;
    const int m0 = blockIdx.y * 64;
    const long aoff = (long)b * a_bstride;
    const long xoff = (long)b * (long)K * N;

    __shared__ float As[16][68];   // 64->68 pad keeps 16B align, kills conflicts
    __shared__ float Bs[16][68];

    const int t  = threadIdx.x;
    const int tx = t & 15;          // n sub-tile
    const int ty = t >> 4;          // m sub-tile
    const int lr = t >> 4;          // load row (k) 0..15
    const int lc = (t & 15) * 4;    // load col 0..60

    float acc[4][4];
    #pragma unroll
    for (int i = 0; i < 4; ++i)
        #pragma unroll
        for (int j = 0; j < 4; ++j) acc[i][j] = 0.f;

    for (int k0 = 0; k0 < K; k0 += 16) {
        float av[4], xv[4];
        load4(A, aoff + (long)(k0 + lr) * M + m0 + lc, f32in, av);
        load4(X, xoff + (long)(k0 + lr) * N + n0 + lc, f32in, xv);
        As[lr][lc + 0] = av[0]; As[lr][lc + 1] = av[1];
        As[lr][lc + 2] = av[2]; As[lr][lc + 3] = av[3];
        Bs[lr][lc + 0] = xv[0]; Bs[lr][lc + 1] = xv[1];
        Bs[lr][lc + 2] = xv[2]; Bs[lr][lc + 3] = xv[3];
        __syncthreads();
        #pragma unroll
        for (int kk = 0; kk < 16; ++kk) {
            float a[4], bv[4];
            #pragma unroll
            for (int i = 0; i < 4; ++i) a[i]  = As[kk][ty * 4 + i];
            #pragma unroll
            for (int j = 0; j < 4; ++j) bv[j] = Bs[kk][tx * 4 + j];
            #pragma unroll
            for (int i = 0; i < 4; ++i)
                #pragma unroll
                for (int j = 0; j < 4; ++j) acc[i][j] += a[i] * bv[j];
        }
        __syncthreads();
    }

    float bi[4] = {0.f, 0.f, 0.f, 0.f};
    if (bias) {
        #pragma unroll
        for (int i = 0; i < 4; ++i)
            bi[i] = f32io ? ((const float*)bias)[m0 + ty * 4 + i]
                          : bf2f(((const unsigned short*)bias)[m0 + ty * 4 + i]);
    }
    #pragma unroll
    for (int i = 0; i < 4; ++i) {
        long coff = ((long)b * M + m0 + ty * 4 + i) * N + n0 + tx * 4;
        if (f32io) {
            float4 o;
            o.x = acc[i][0] + bi[i]; o.y = acc[i][1] + bi[i];
            o.z = acc[i][2] + bi[i]; o.w = acc[i][3] + bi[i];
            *(float4*)((float*)C + coff) = o;
        } else {
            ushort4 o;
            o.x = f2bf(acc[i][0] + bi[i]); o.y = f2bf(acc[i][1] + bi[i]);
            o.z = f2bf(acc[i][2] + bi[i]); o.w = f2bf(acc[i][3] + bi[i]);
            *(ushort4*)((unsigned short*)C + coff) = o;
        }
    }
}

// In-place row softmax over n (1024 elems/row), rows = B*512. bf16 data.
__global__ __launch_bounds__(256) void softmax_rows(unsigned short* __restrict__ Kt)
{
    const long row = blockIdx.x;
    unsigned short* p = Kt + row * 1024;
    const int t = threadIdx.x;

    ushort4 raw = *(const ushort4*)(p + t * 4);
    float f[4] = {bf2f(raw.x), bf2f(raw.y), bf2f(raw.z), bf2f(raw.w)};

    float m = fmaxf(fmaxf(f[0], f[1]), fmaxf(f[2], f[3]));
    m = waveReduceMax(m);
    __shared__ float redm[4], reds[4];
    if ((t & 63) == 0) redm[t >> 6] = m;
    __syncthreads();
    m = fmaxf(fmaxf(redm[0], redm[1]), fmaxf(redm[2], redm[3]));

    float e[4], s = 0.f;
    #pragma unroll
    for (int i = 0; i < 4; ++i) { e[i] = expf(f[i] - m); s += e[i]; }
    s = waveReduceSum(s);
    if ((t & 63) == 0) reds[t >> 6] = s;
    __syncthreads();
    s = reds[0] + reds[1] + reds[2] + reds[3];
    const float inv = 1.0f / s;

    ushort4 o;
    o.x = f2bf(e[0] * inv); o.y = f2bf(e[1] * inv);
    o.z = f2bf(e[2] * inv); o.w = f2bf(e[3] * inv);
    *(ushort4*)(p + t * 4) = o;
}

// ctx[b,h,d,v] = sum_n Ksm[b,h*64+d,n] * Vt[b,h*64+v,n]   (K=1024), bf16 in
__global__ __launch_bounds__(256) void ctx_kernel(
    const unsigned short* __restrict__ Ksm,
    const unsigned short* __restrict__ Vt,
    float* __restrict__ ctx)
{
    const int bh = blockIdx.x;                 // b*8 + h
    const long base = (long)(bh >> 3) * 512 * 1024 + (long)(bh & 7) * 64 * 1024;
    const unsigned short* Kb = Ksm + base;
    const unsigned short* Vb = Vt + base;

    __shared__ float Ks[64][33];
    __shared__ float Vs[64][33];

    const int t = threadIdx.x;
    const int tx = t & 15, ty = t >> 4;
    const int lrow = t >> 2;                   // 0..63
    const int lcol = (t & 3) * 8;              // 0,8,16,24

    float acc[4][4];
    #pragma unroll
    for (int i = 0; i < 4; ++i)
        #pragma unroll
        for (int j = 0; j < 4; ++j) acc[i][j] = 0.f;

    for (int nn0 = 0; nn0 < 1024; nn0 += 32) {
        ushort4 k0 = *(const ushort4*)(Kb + (long)lrow * 1024 + nn0 + lcol);
        ushort4 k1 = *(const ushort4*)(Kb + (long)lrow * 1024 + nn0 + lcol + 4);
        ushort4 v0 = *(const ushort4*)(Vb + (long)lrow * 1024 + nn0 + lcol);
        ushort4 v1 = *(const ushort4*)(Vb + (long)lrow * 1024 + nn0 + lcol + 4);
        Ks[lrow][lcol + 0] = bf2f(k0.x); Ks[lrow][lcol + 1] = bf2f(k0.y);
        Ks[lrow][lcol + 2] = bf2f(k0.z); Ks[lrow][lcol + 3] = bf2f(k0.w);
        Ks[lrow][lcol + 4] = bf2f(k1.x); Ks[lrow][lcol + 5] = bf2f(k1.y);
        Ks[lrow][lcol + 6] = bf2f(k1.z); Ks[lrow][lcol + 7] = bf2f(k1.w);
        Vs[lrow][lcol + 0] = bf2f(v0.x); Vs[lrow][lcol + 1] = bf2f(v0.y);
        Vs[lrow][lcol + 2] = bf2f(v0.z); Vs[lrow][lcol + 3] = bf2f(v0.w);
        Vs[lrow][lcol + 4] = bf2f(v1.x); Vs[lrow][lcol + 5] = bf2f(v1.y);
        Vs[lrow][lcol + 6] = bf2f(v1.z); Vs[lrow][lcol + 7] = bf2f(v1.w);
        __syncthreads();
        #pragma unroll
        for (int n = 0; n < 32; ++n) {
            float a[4], bv[4];
            #pragma unroll
            for (int i = 0; i < 4; ++i) a[i]  = Ks[ty * 4 + i][n];
            #pragma unroll
            for (int j = 0; j < 4; ++j) bv[j] = Vs[tx * 4 + j][n];
            #pragma unroll
            for (int i = 0; i < 4; ++i)
                #pragma unroll
                for (int j = 0; j < 4; ++j) acc[i][j] += a[i] * bv[j];
        }
        __syncthreads();
    }
    #pragma unroll
    for (int i = 0; i < 4; ++i)
        #pragma unroll
        for (int j = 0; j < 4; ++j)
            ctx[((long)bh * 64 + ty * 4 + i) * 64 + tx * 4 + j] = acc[i][j];
}

// Weff[b][h*64+d][c] = sum_v ctx[b,h,d,v] * Wp[h*64+v, c];  Wp dtype per flag
__global__ __launch_bounds__(256) void weff_kernel(
    const float* __restrict__ ctx,          // [B,8,64,64] fp32
    const void* __restrict__ Wp,            // [512,512] flag dtype
    unsigned short* __restrict__ Weff,      // [B,512,512] bf16
    const int* __restrict__ flag)
{
    const int fl = *flag;
    const bool f32 = (fl == 0);
    const int c0 = blockIdx.x * 64;
    const int h  = blockIdx.y;
    const int b  = blockIdx.z;

    __shared__ float Cs[64][68];
    __shared__ float Ws[64][68];

    const int t = threadIdx.x;
    const int tx = t & 15, ty = t >> 4;

    const float* cb = ctx + ((long)b * 8 + h) * 4096;
    for (int i = t; i < 4096; i += 256) Cs[i >> 6][i & 63] = cb[i];
    for (int i = t; i < 4096; i += 256) {
        int v = i >> 6, c = i & 63;
        long idx = (long)(h * 64 + v) * 512 + c0 + c;
        Ws[v][c] = f32 ? ((const float*)Wp)[idx]
                       : bf2f(((const unsigned short*)Wp)[idx]);
    }
    __syncthreads();

    float acc[4][4];
    #pragma unroll
    for (int i = 0; i < 4; ++i)
        #pragma unroll
        for (int j = 0; j < 4; ++j) acc[i][j] = 0.f;

    #pragma unroll
    for (int v = 0; v < 64; ++v) {
        float a[4], w[4];
        #pragma unroll
        for (int i = 0; i < 4; ++i) a[i] = Cs[ty * 4 + i][v];
        #pragma unroll
        for (int j = 0; j < 4; ++j) w[j] = Ws[v][tx * 4 + j];
        #pragma unroll
        for (int i = 0; i < 4; ++i)
            #pragma unroll
            for (int j = 0; j < 4; ++j) acc[i][j] += a[i] * w[j];
    }
    #pragma unroll
    for (int i = 0; i < 4; ++i)
        #pragma unroll
        for (int j = 0; j < 4; ++j)
            Weff[((long)b * 512 + h * 64 + ty * 4 + i) * 512 + c0 + tx * 4 + j]
                = f2bf(acc[i][j]);
}

extern "C" void kernel_launch(void* const* d_in, const int* in_sizes, int n_in,
                              void* d_out, int out_size, void* d_ws, size_t ws_size,
                              hipStream_t stream) {
    const void* x  = d_in[0];   // [32,512,1024]
    const void* Wq = d_in[1];   // [512,512]
    const void* Wk = d_in[2];
    const void* Wv = d_in[3];
    const void* Wp = d_in[4];   // [512,512]
    const void* bp = d_in[5];   // [512]

    char* ws = (char*)d_ws;
    unsigned short* Qt   = (unsigned short*)(ws);                // 32 MB
    unsigned short* Kt   = (unsigned short*)(ws + 33554432ll);   // 32 MB
    unsigned short* Vt   = (unsigned short*)(ws + 67108864ll);   // 32 MB
    float*          ctx  = (float*)(ws + 100663296ll);           //  4 MB
    unsigned short* Weff = (unsigned short*)(ws + 104857600ll);  // 16 MB
    int*            flag = (int*)(ws + 121634816ll);             //  4 B  (@116MB)

    detect_dtype<<<dim3(1), dim3(64), 0, stream>>>((const unsigned short*)x, flag);

    dim3 gg(16, 8, 32);   // (N/64, M/64, B)
    dim3 bb(256);
    gemm_wt_x<<<gg, bb, 0, stream>>>(Wq, 0, x, nullptr, Qt, 512, 1024, 512, flag, 1, 0);
    gemm_wt_x<<<gg, bb, 0, stream>>>(Wk, 0, x, nullptr, Kt, 512, 1024, 512, flag, 1, 0);
    gemm_wt_x<<<gg, bb, 0, stream>>>(Wv, 0, x, nullptr, Vt, 512, 1024, 512, flag, 1, 0);
    softmax_rows<<<dim3(16384), bb, 0, stream>>>(Kt);
    ctx_kernel<<<dim3(256), bb, 0, stream>>>(Kt, Vt, ctx);
    weff_kernel<<<dim3(8, 8, 32), bb, 0, stream>>>(ctx, Wp, Weff, flag);
    gemm_wt_x<<<gg, bb, 0, stream>>>(Weff, 512ll * 512, Qt, bp, d_out, 512, 1024, 512, flag, 0, 1);
}

// Round 4
// 469.495 us; speedup vs baseline: 2.4633x; 2.4633x over previous
//
#include <hip/hip_runtime.h>
#include <hip/hip_bf16.h>

// Round 4: round-3 structure, but GEMM staging via explicit vector loads +
// ds_write_b128 (register round-trip) instead of global_load_lds — round 3's
// abort is attributed to the async-staging builtin with a runtime-varying
// wave LDS base. Everything else (layouts, MFMA frags, stores) unchanged.
//
// Pipeline (bf16 intermediates, k-contiguous for MFMA):
//   Xt[b][n][c]   = x transposed+converted          (buf1, 32 MB)
//   WqT/WkT/WvT[hd][c]                              (WT, 1.5 MB)
//   Kc[b][hd][n]  = gemm_bt(Xt, WkT) mode1          (buf2)
//   Vc[b][hd][n]  = gemm_bt(Xt, WvT) mode1          (buf3)
//   softmax rows of Kc (over n, contiguous)
//   ctx[b,h,d,v]  = sum_n Kc*Vc   (VALU, fp32)      (ctxbuf, 4 MB)
//   WeffT[b][c][hd] = sum_v ctx*Wp                  (buf3 reuse)
//   Q[b][n][hd]   = gemm_bt(Xt, WqT) mode0          (buf2 reuse)
//   out[b][c][n]  = gemm_bt(WeffT, Q) mode2 (+bp)   -> d_out

__device__ __forceinline__ float bf2f(unsigned short u) {
    union { unsigned int i; float f; } x;
    x.i = ((unsigned int)u) << 16;
    return x.f;
}
__device__ __forceinline__ unsigned short f2bf(float f) {
    unsigned int u = __float_as_uint(f);
    unsigned int lsb = (u >> 16) & 1u;
    u += 0x7fffu + lsb;             // RNE
    return (unsigned short)(u >> 16);
}
__device__ __forceinline__ float waveReduceMax(float v) {
    #pragma unroll
    for (int off = 32; off > 0; off >>= 1) v = fmaxf(v, __shfl_xor(v, off, 64));
    return v;
}
__device__ __forceinline__ float waveReduceSum(float v) {
    #pragma unroll
    for (int off = 32; off > 0; off >>= 1) v += __shfl_xor(v, off, 64);
    return v;
}

typedef __bf16 bf16x8 __attribute__((ext_vector_type(8)));
typedef float  f32x4  __attribute__((ext_vector_type(4)));

// flag: 1 = inputs are bf16, 0 = fp32 (detected at runtime)
__global__ void detect_dtype(const unsigned short* __restrict__ x, int* __restrict__ flag)
{
    int t = threadIdx.x;                      // 64 threads
    unsigned short u = x[2 * t];
    int e = (u >> 7) & 0xFF;
    int sane = (e >= 113 && e <= 142) ? 1 : 0;
    #pragma unroll
    for (int off = 32; off > 0; off >>= 1) sane += __shfl_xor(sane, off, 64);
    if (t == 0) *flag = (sane >= 32) ? 1 : 0;
}

// Generic transpose+convert: in [Ri][Ci] (flag dtype) -> out [Ci][Ri] bf16.
__global__ __launch_bounds__(256) void transpose_conv(
    const void* __restrict__ in, long in_bstride,
    unsigned short* __restrict__ out, long out_bstride,
    int Ri, int Ci, const int* __restrict__ flag)
{
    const int fl = *flag;
    const int b  = blockIdx.z;
    const int c0 = blockIdx.x * 64;
    const int r0 = blockIdx.y * 64;
    __shared__ unsigned short Ts[64][68];
    const int t   = threadIdx.x;
    const int tr  = t >> 4;                 // 0..15
    const int tc4 = (t & 15) * 4;
    #pragma unroll
    for (int rr = 0; rr < 4; ++rr) {
        int rl = rr * 16 + tr;
        long off = (long)b * in_bstride + (long)(r0 + rl) * Ci + c0 + tc4;
        unsigned short v[4];
        if (fl) {
            ushort4 u = *(const ushort4*)((const unsigned short*)in + off);
            v[0] = u.x; v[1] = u.y; v[2] = u.z; v[3] = u.w;
        } else {
            float4 u = *(const float4*)((const float*)in + off);
            v[0] = f2bf(u.x); v[1] = f2bf(u.y); v[2] = f2bf(u.z); v[3] = f2bf(u.w);
        }
        #pragma unroll
        for (int q = 0; q < 4; ++q) Ts[tc4 + q][rl] = v[q];
    }
    __syncthreads();
    #pragma unroll
    for (int rr = 0; rr < 4; ++rr) {
        int cl = rr * 16 + tr;
        ushort4 o = *(const ushort4*)&Ts[cl][tc4];
        *(ushort4*)(out + (long)b * out_bstride + (long)(c0 + cl) * Ri + r0 + tc4) = o;
    }
}

// C = A . B^T : A [M][K] bf16 k-contig, B [N][K] bf16 k-contig, fp32 acc.
// Block tile 128x128, 4 waves each 64x64 (4x4 MFMA 16x16x32 tiles), BK=32.
// Staging: each thread loads 2x16B of A and B, round-trips through regs.
// mode 0: C bf16 row-major [M][N]
// mode 1: C bf16 transposed [N][M]
// mode 2: C [M][N] + bias[m]; C/bias dtype per flag (1=bf16, 0=fp32)
__global__ __launch_bounds__(256) void gemm_bt_mfma(
    const unsigned short* __restrict__ A, long a_bstride,
    const unsigned short* __restrict__ Bm, long b_bstride,
    void* __restrict__ C, long c_bstride,
    const void* __restrict__ bias,
    int M, int N, int K, int mode,
    const int* __restrict__ flag)
{
    const int b  = blockIdx.z;
    const int n0 = blockIdx.x * 128;
    const int m0 = blockIdx.y * 128;
    const unsigned short* Ab = A  + (long)b * a_bstride;
    const unsigned short* Bb = Bm + (long)b * b_bstride;

    __shared__ unsigned short As[128 * 32];   // element (row,k) at As[row*32+k]
    __shared__ unsigned short Bs[128 * 32];

    const int t    = threadIdx.x;
    const int w    = t >> 6;
    const int lane = t & 63;
    const int wm   = (w & 1) * 64;
    const int wn   = (w >> 1) * 64;
    const int fm   = lane & 15;     // m (A-frag) / n (B-frag) index
    const int kg   = lane >> 4;     // k-group

    const int srow = t >> 2;        // staging row 0..63 (plus +64)
    const int scol = (t & 3) * 8;   // staging col in elements

    f32x4 acc[4][4] = {};

    for (int k0 = 0; k0 < K; k0 += 32) {
        uint4 a0 = *(const uint4*)(Ab + (long)(m0 + srow)      * K + k0 + scol);
        uint4 a1 = *(const uint4*)(Ab + (long)(m0 + srow + 64) * K + k0 + scol);
        uint4 b0 = *(const uint4*)(Bb + (long)(n0 + srow)      * K + k0 + scol);
        uint4 b1 = *(const uint4*)(Bb + (long)(n0 + srow + 64) * K + k0 + scol);
        __syncthreads();            // prev iter's frag reads done before overwrite
        *(uint4*)&As[srow * 32 + scol]        = a0;
        *(uint4*)&As[(srow + 64) * 32 + scol] = a1;
        *(uint4*)&Bs[srow * 32 + scol]        = b0;
        *(uint4*)&Bs[(srow + 64) * 32 + scol] = b1;
        __syncthreads();

        bf16x8 af[4], bf[4];
        #pragma unroll
        for (int i = 0; i < 4; ++i)
            af[i] = *(const bf16x8*)&As[(wm + i * 16 + fm) * 32 + kg * 8];
        #pragma unroll
        for (int j = 0; j < 4; ++j)
            bf[j] = *(const bf16x8*)&Bs[(wn + j * 16 + fm) * 32 + kg * 8];
        #pragma unroll
        for (int i = 0; i < 4; ++i)
            #pragma unroll
            for (int j = 0; j < 4; ++j)
                acc[i][j] = __builtin_amdgcn_mfma_f32_16x16x32_bf16(
                    af[i], bf[j], acc[i][j], 0, 0, 0);
    }

    // D layout (m89-verified): col(n) = lane&15, row(m) = (lane>>4)*4 + reg
    const int fl = *flag;
    const long cb = (long)b * c_bstride;
    #pragma unroll
    for (int i = 0; i < 4; ++i) {
        #pragma unroll
        for (int j = 0; j < 4; ++j) {
            const int n = n0 + wn + j * 16 + fm;
            #pragma unroll
            for (int r = 0; r < 4; ++r) {
                const int m = m0 + wm + i * 16 + kg * 4 + r;
                const float val = acc[i][j][r];
                if (mode == 0) {
                    ((unsigned short*)C)[cb + (long)m * N + n] = f2bf(val);
                } else if (mode == 1) {
                    ((unsigned short*)C)[cb + (long)n * M + m] = f2bf(val);
                } else {
                    float bv = 0.f;
                    if (bias) bv = fl ? bf2f(((const unsigned short*)bias)[m])
                                      : ((const float*)bias)[m];
                    const long off = cb + (long)m * N + n;
                    if (fl) ((unsigned short*)C)[off] = f2bf(val + bv);
                    else    ((float*)C)[off] = val + bv;
                }
            }
        }
    }
}

// In-place row softmax over n (1024 elems/row), rows = B*512. bf16 data.
__global__ __launch_bounds__(256) void softmax_rows(unsigned short* __restrict__ Kt)
{
    const long row = blockIdx.x;
    unsigned short* p = Kt + row * 1024;
    const int t = threadIdx.x;

    ushort4 raw = *(const ushort4*)(p + t * 4);
    float f[4] = {bf2f(raw.x), bf2f(raw.y), bf2f(raw.z), bf2f(raw.w)};

    float m = fmaxf(fmaxf(f[0], f[1]), fmaxf(f[2], f[3]));
    m = waveReduceMax(m);
    __shared__ float redm[4], reds[4];
    if ((t & 63) == 0) redm[t >> 6] = m;
    __syncthreads();
    m = fmaxf(fmaxf(redm[0], redm[1]), fmaxf(redm[2], redm[3]));

    float e[4], s = 0.f;
    #pragma unroll
    for (int i = 0; i < 4; ++i) { e[i] = expf(f[i] - m); s += e[i]; }
    s = waveReduceSum(s);
    if ((t & 63) == 0) reds[t >> 6] = s;
    __syncthreads();
    s = reds[0] + reds[1] + reds[2] + reds[3];
    const float inv = 1.0f / s;

    ushort4 o;
    o.x = f2bf(e[0] * inv); o.y = f2bf(e[1] * inv);
    o.z = f2bf(e[2] * inv); o.w = f2bf(e[3] * inv);
    *(ushort4*)(p + t * 4) = o;
}

// ctx[b,h,d,v] = sum_n Ksm[b,h*64+d,n] * Vt[b,h*64+v,n]   (K=1024), bf16 in
__global__ __launch_bounds__(256) void ctx_kernel(
    const unsigned short* __restrict__ Ksm,
    const unsigned short* __restrict__ Vt,
    float* __restrict__ ctx)
{
    const int bh = blockIdx.x;                 // b*8 + h
    const long base = (long)(bh >> 3) * 512 * 1024 + (long)(bh & 7) * 64 * 1024;
    const unsigned short* Kb = Ksm + base;
    const unsigned short* Vb = Vt + base;

    __shared__ float Ks[64][33];
    __shared__ float Vs[64][33];

    const int t = threadIdx.x;
    const int tx = t & 15, ty = t >> 4;
    const int lrow = t >> 2;                   // 0..63
    const int lcol = (t & 3) * 8;              // 0,8,16,24

    float acc[4][4];
    #pragma unroll
    for (int i = 0; i < 4; ++i)
        #pragma unroll
        for (int j = 0; j < 4; ++j) acc[i][j] = 0.f;

    for (int nn0 = 0; nn0 < 1024; nn0 += 32) {
        ushort4 k0 = *(const ushort4*)(Kb + (long)lrow * 1024 + nn0 + lcol);
        ushort4 k1 = *(const ushort4*)(Kb + (long)lrow * 1024 + nn0 + lcol + 4);
        ushort4 v0 = *(const ushort4*)(Vb + (long)lrow * 1024 + nn0 + lcol);
        ushort4 v1 = *(const ushort4*)(Vb + (long)lrow * 1024 + nn0 + lcol + 4);
        Ks[lrow][lcol + 0] = bf2f(k0.x); Ks[lrow][lcol + 1] = bf2f(k0.y);
        Ks[lrow][lcol + 2] = bf2f(k0.z); Ks[lrow][lcol + 3] = bf2f(k0.w);
        Ks[lrow][lcol + 4] = bf2f(k1.x); Ks[lrow][lcol + 5] = bf2f(k1.y);
        Ks[lrow][lcol + 6] = bf2f(k1.z); Ks[lrow][lcol + 7] = bf2f(k1.w);
        Vs[lrow][lcol + 0] = bf2f(v0.x); Vs[lrow][lcol + 1] = bf2f(v0.y);
        Vs[lrow][lcol + 2] = bf2f(v0.z); Vs[lrow][lcol + 3] = bf2f(v0.w);
        Vs[lrow][lcol + 4] = bf2f(v1.x); Vs[lrow][lcol + 5] = bf2f(v1.y);
        Vs[lrow][lcol + 6] = bf2f(v1.z); Vs[lrow][lcol + 7] = bf2f(v1.w);
        __syncthreads();
        #pragma unroll
        for (int n = 0; n < 32; ++n) {
            float a[4], bv[4];
            #pragma unroll
            for (int i = 0; i < 4; ++i) a[i]  = Ks[ty * 4 + i][n];
            #pragma unroll
            for (int j = 0; j < 4; ++j) bv[j] = Vs[tx * 4 + j][n];
            #pragma unroll
            for (int i = 0; i < 4; ++i)
                #pragma unroll
                for (int j = 0; j < 4; ++j) acc[i][j] += a[i] * bv[j];
        }
        __syncthreads();
    }
    #pragma unroll
    for (int i = 0; i < 4; ++i)
        #pragma unroll
        for (int j = 0; j < 4; ++j)
            ctx[((long)bh * 64 + ty * 4 + i) * 64 + tx * 4 + j] = acc[i][j];
}

// WeffT[b][c][h*64+d] = sum_v ctx[b,h,d,v] * Wp[h*64+v][c]
__global__ __launch_bounds__(256) void weff_kernel(
    const float* __restrict__ ctx,          // [B,8,64,64] fp32
    const void* __restrict__ Wp,            // [512,512] flag dtype, c-contig
    unsigned short* __restrict__ WeffT,     // [B,512,512] bf16, hd-contig
    const int* __restrict__ flag)
{
    const int fl = *flag;
    const int c0 = blockIdx.x * 64;
    const int h  = blockIdx.y;
    const int b  = blockIdx.z;

    __shared__ float Cs[64][65];   // [d][v]
    __shared__ float Ws[64][68];   // [v][c]

    const int t = threadIdx.x;
    const int tx = t & 15, ty = t >> 4;

    const float* cb = ctx + ((long)b * 8 + h) * 4096;
    for (int i = t; i < 4096; i += 256) Cs[i >> 6][i & 63] = cb[i];
    for (int i = t; i < 4096; i += 256) {
        int v = i >> 6, c = i & 63;
        long idx = (long)(h * 64 + v) * 512 + c0 + c;
        Ws[v][c] = fl ? bf2f(((const unsigned short*)Wp)[idx])
                      : ((const float*)Wp)[idx];
    }
    __syncthreads();

    float acc[4][4];
    #pragma unroll
    for (int i = 0; i < 4; ++i)
        #pragma unroll
        for (int j = 0; j < 4; ++j) acc[i][j] = 0.f;

    #pragma unroll
    for (int v = 0; v < 64; ++v) {
        float a[4], d[4];
        #pragma unroll
        for (int i = 0; i < 4; ++i) a[i] = Ws[v][ty * 4 + i];   // over c
        #pragma unroll
        for (int j = 0; j < 4; ++j) d[j] = Cs[tx * 4 + j][v];   // over d
        #pragma unroll
        for (int i = 0; i < 4; ++i)
            #pragma unroll
            for (int j = 0; j < 4; ++j) acc[i][j] += a[i] * d[j];
    }
    #pragma unroll
    for (int i = 0; i < 4; ++i) {
        ushort4 o;
        o.x = f2bf(acc[i][0]); o.y = f2bf(acc[i][1]);
        o.z = f2bf(acc[i][2]); o.w = f2bf(acc[i][3]);
        *(ushort4*)&WeffT[((long)b * 512 + c0 + ty * 4 + i) * 512 + h * 64 + tx * 4] = o;
    }
}

extern "C" void kernel_launch(void* const* d_in, const int* in_sizes, int n_in,
                              void* d_out, int out_size, void* d_ws, size_t ws_size,
                              hipStream_t stream) {
    const void* x  = d_in[0];   // [32,512,1024] flag dtype
    const void* Wq = d_in[1];   // [512,512] (c rows, hd cols)
    const void* Wk = d_in[2];
    const void* Wv = d_in[3];
    const void* Wp = d_in[4];   // [512,512] (hd rows, c cols)
    const void* bp = d_in[5];   // [512]

    char* ws = (char*)d_ws;
    unsigned short* Xt   = (unsigned short*)(ws);                // 32 MB [b][n][c]
    unsigned short* buf2 = (unsigned short*)(ws + 33554432ll);   // 32 MB Kc -> Q
    unsigned short* buf3 = (unsigned short*)(ws + 67108864ll);   // 32 MB Vc -> WeffT
    float*          ctx  = (float*)(ws + 100663296ll);           //  4 MB
    unsigned short* WT   = (unsigned short*)(ws + 104857600ll);  // 1.5 MB
    int*            flag = (int*)(ws + 106430464ll);

    detect_dtype<<<dim3(1), dim3(64), 0, stream>>>((const unsigned short*)x, flag);

    // x [b][512 c][1024 n] -> Xt [b][1024 n][512 c]
    transpose_conv<<<dim3(16, 8, 32), 256, 0, stream>>>(
        x, 512ll * 1024, Xt, 1024ll * 512, 512, 1024, flag);
    // W [512 c][512 hd] -> WT [512 hd][512 c]
    transpose_conv<<<dim3(8, 8, 1), 256, 0, stream>>>(Wq, 0, WT,          0, 512, 512, flag);
    transpose_conv<<<dim3(8, 8, 1), 256, 0, stream>>>(Wk, 0, WT + 262144, 0, 512, 512, flag);
    transpose_conv<<<dim3(8, 8, 1), 256, 0, stream>>>(Wv, 0, WT + 524288, 0, 512, 512, flag);

    const long XB = 1024ll * 512;   // Xt batch stride
    // Kc[b][hd][n] (mode 1), Vc[b][hd][n] (mode 1)
    gemm_bt_mfma<<<dim3(4, 8, 32), 256, 0, stream>>>(
        Xt, XB, WT + 262144, 0, buf2, XB, nullptr, 1024, 512, 512, 1, flag);
    gemm_bt_mfma<<<dim3(4, 8, 32), 256, 0, stream>>>(
        Xt, XB, WT + 524288, 0, buf3, XB, nullptr, 1024, 512, 512, 1, flag);

    softmax_rows<<<dim3(16384), 256, 0, stream>>>(buf2);
    ctx_kernel<<<dim3(256), 256, 0, stream>>>(buf2, buf3, ctx);
    weff_kernel<<<dim3(8, 8, 32), 256, 0, stream>>>(ctx, Wp, buf3, flag);

    // Q[b][n][hd] (mode 0) into buf2 (Kc dead after ctx)
    gemm_bt_mfma<<<dim3(4, 8, 32), 256, 0, stream>>>(
        Xt, XB, WT, 0, buf2, XB, nullptr, 1024, 512, 512, 0, flag);

    // out[b][c][n] = WeffT[b] . Q[b]^T + bp (mode 2, dtype per flag)
    gemm_bt_mfma<<<dim3(8, 4, 32), 256, 0, stream>>>(
        buf3, 512ll * 512, buf2, XB, d_out, 512ll * 1024, bp,
        512, 1024, 512, 2, flag);
}

// Round 6
// 337.263 us; speedup vs baseline: 3.4291x; 1.3921x over previous
//
#include <hip/hip_runtime.h>
#include <hip/hip_bf16.h>

// Round 6: identical to round 5 except the transpose_x output stride fix
// (wrote Xt rows with stride 1024 instead of 512 -> scrambled Xt, garbage
// downstream). Round-5 structure: row-major stores everywhere via operand
// swap, K+V merged gemm, register-prefetch K-loop, MFMA ctx with direct
// global fragment loads.
//
// Pipeline:
//   Xt[b][n][c]    = x transposed+converted        @0      (32 MB)
//   WT = [WqT | WkT | WvT] [hd][c]                 @121634816 (1.5 MB)
//   KV[b][hd2][n]  = gemm(A=[WkT;WvT], B=Xt)       @33554432 (64 MB)
//                    rows 0-511 = K, 512-1023 = V
//   softmax over n on K rows (in place)
//   ctx[b,h,d,v]   = MFMA K.V^T per (b,h)          @100663296 (4 MB fp32)
//   WeffT[b][c][hd]= sum_v ctx*Wp                  @104857600 (16 MB)
//   Q[b][n][hd]    = gemm(A=Xt, B=WqT)             @33554432 (reuse, KV dead)
//   out[b][c][n]   = gemm(A=WeffT, B=Q) + bp       -> d_out

__device__ __forceinline__ float bf2f(unsigned short u) {
    union { unsigned int i; float f; } x;
    x.i = ((unsigned int)u) << 16;
    return x.f;
}
__device__ __forceinline__ unsigned short f2bf(float f) {
    unsigned int u = __float_as_uint(f);
    unsigned int lsb = (u >> 16) & 1u;
    u += 0x7fffu + lsb;             // RNE
    return (unsigned short)(u >> 16);
}
__device__ __forceinline__ float waveReduceMax(float v) {
    #pragma unroll
    for (int off = 32; off > 0; off >>= 1) v = fmaxf(v, __shfl_xor(v, off, 64));
    return v;
}
__device__ __forceinline__ float waveReduceSum(float v) {
    #pragma unroll
    for (int off = 32; off > 0; off >>= 1) v += __shfl_xor(v, off, 64);
    return v;
}

typedef __bf16 bf16x8 __attribute__((ext_vector_type(8)));
typedef float  f32x4  __attribute__((ext_vector_type(4)));

// flag: 1 = inputs are bf16, 0 = fp32 (detected at runtime)
__global__ void detect_dtype(const unsigned short* __restrict__ x, int* __restrict__ flag)
{
    int t = threadIdx.x;                      // 64 threads
    unsigned short u = x[2 * t];
    int e = (u >> 7) & 0xFF;
    int sane = (e >= 113 && e <= 142) ? 1 : 0;
    #pragma unroll
    for (int off = 32; off > 0; off >>= 1) sane += __shfl_xor(sane, off, 64);
    if (t == 0) *flag = (sane >= 32) ? 1 : 0;
}

// x [b][512 c][1024 n] (flag dtype) -> Xt [b][n][c] bf16 (row stride 512!)
__global__ __launch_bounds__(256) void transpose_x(
    const void* __restrict__ in, unsigned short* __restrict__ out,
    const int* __restrict__ flag)
{
    const int fl = *flag;
    const int b  = blockIdx.z;
    const int c0 = blockIdx.x * 64;   // over n (1024)
    const int r0 = blockIdx.y * 64;   // over c (512)
    __shared__ unsigned short Ts[64][68];
    const int t   = threadIdx.x;
    const int tr  = t >> 4;
    const int tc4 = (t & 15) * 4;
    #pragma unroll
    for (int rr = 0; rr < 4; ++rr) {
        int rl = rr * 16 + tr;
        long off = (long)b * 524288 + (long)(r0 + rl) * 1024 + c0 + tc4;
        unsigned short v[4];
        if (fl) {
            ushort4 u = *(const ushort4*)((const unsigned short*)in + off);
            v[0] = u.x; v[1] = u.y; v[2] = u.z; v[3] = u.w;
        } else {
            float4 u = *(const float4*)((const float*)in + off);
            v[0] = f2bf(u.x); v[1] = f2bf(u.y); v[2] = f2bf(u.z); v[3] = f2bf(u.w);
        }
        #pragma unroll
        for (int q = 0; q < 4; ++q) Ts[tc4 + q][rl] = v[q];
    }
    __syncthreads();
    #pragma unroll
    for (int rr = 0; rr < 4; ++rr) {
        int cl = rr * 16 + tr;
        ushort4 o = *(const ushort4*)&Ts[cl][tc4];
        // Xt row (n = c0+cl) has 512 elements (c-dim) -> stride 512
        *(ushort4*)(out + (long)b * 524288 + (long)(c0 + cl) * 512 + r0 + tc4) = o;
    }
}

// W [512 c][512 hd] -> WT + z*262144 [512 hd][512 c], z picks Wq/Wk/Wv
__global__ __launch_bounds__(256) void transpose_w3(
    const void* __restrict__ w0, const void* __restrict__ w1,
    const void* __restrict__ w2, unsigned short* __restrict__ out,
    const int* __restrict__ flag)
{
    const int fl = *flag;
    const int z  = blockIdx.z;
    const void* in = (z == 0) ? w0 : (z == 1) ? w1 : w2;
    unsigned short* op = out + (long)z * 262144;
    const int c0 = blockIdx.x * 64;
    const int r0 = blockIdx.y * 64;
    __shared__ unsigned short Ts[64][68];
    const int t   = threadIdx.x;
    const int tr  = t >> 4;
    const int tc4 = (t & 15) * 4;
    #pragma unroll
    for (int rr = 0; rr < 4; ++rr) {
        int rl = rr * 16 + tr;
        long off = (long)(r0 + rl) * 512 + c0 + tc4;
        unsigned short v[4];
        if (fl) {
            ushort4 u = *(const ushort4*)((const unsigned short*)in + off);
            v[0] = u.x; v[1] = u.y; v[2] = u.z; v[3] = u.w;
        } else {
            float4 u = *(const float4*)((const float*)in + off);
            v[0] = f2bf(u.x); v[1] = f2bf(u.y); v[2] = f2bf(u.z); v[3] = f2bf(u.w);
        }
        #pragma unroll
        for (int q = 0; q < 4; ++q) Ts[tc4 + q][rl] = v[q];
    }
    __syncthreads();
    #pragma unroll
    for (int rr = 0; rr < 4; ++rr) {
        int cl = rr * 16 + tr;
        ushort4 o = *(const ushort4*)&Ts[cl][tc4];
        *(ushort4*)(op + (long)(c0 + cl) * 512 + r0 + tc4) = o;
    }
}

// C = A . B^T : A [M][K] bf16 k-contig, B [N][K] bf16 k-contig, fp32 acc.
// 128x128 block tile, 4 waves of 64x64, BK=32, register-prefetch pipeline.
// mode 0: C bf16 row-major [M][N]
// mode 2: C [M][N] + bias[m]; C/bias dtype per flag (1=bf16, 0=fp32)
__global__ __launch_bounds__(256) void gemm_bt_mfma(
    const unsigned short* __restrict__ A, long a_bstride,
    const unsigned short* __restrict__ Bm, long b_bstride,
    void* __restrict__ C, long c_bstride,
    const void* __restrict__ bias,
    int M, int N, int K, int mode,
    const int* __restrict__ flag)
{
    const int b  = blockIdx.z;
    const int n0 = blockIdx.x * 128;
    const int m0 = blockIdx.y * 128;
    const unsigned short* Ab = A  + (long)b * a_bstride;
    const unsigned short* Bb = Bm + (long)b * b_bstride;

    // rows padded to 40 shorts (80 B): 16B-aligned, breaks pow-2 banking
    __shared__ unsigned short As[128 * 40];
    __shared__ unsigned short Bs[128 * 40];

    const int t    = threadIdx.x;
    const int w    = t >> 6;
    const int lane = t & 63;
    const int wm   = (w & 1) * 64;
    const int wn   = (w >> 1) * 64;
    const int fm   = lane & 15;
    const int kg   = lane >> 4;

    const int srow = t >> 2;        // staging row 0..63 (plus +64)
    const int scol = (t & 3) * 8;   // staging col (elements)

    f32x4 acc[4][4] = {};

    // prefetch k0 = 0
    uint4 a0 = *(const uint4*)(Ab + (long)(m0 + srow)      * K + scol);
    uint4 a1 = *(const uint4*)(Ab + (long)(m0 + srow + 64) * K + scol);
    uint4 b0 = *(const uint4*)(Bb + (long)(n0 + srow)      * K + scol);
    uint4 b1 = *(const uint4*)(Bb + (long)(n0 + srow + 64) * K + scol);

    for (int k0 = 0; k0 < K; k0 += 32) {
        __syncthreads();            // prev iter frag reads done
        *(uint4*)&As[srow * 40 + scol]        = a0;
        *(uint4*)&As[(srow + 64) * 40 + scol] = a1;
        *(uint4*)&Bs[srow * 40 + scol]        = b0;
        *(uint4*)&Bs[(srow + 64) * 40 + scol] = b1;
        __syncthreads();

        if (k0 + 32 < K) {          // prefetch next tile; latency hides under MFMA
            const int kn = k0 + 32;
            a0 = *(const uint4*)(Ab + (long)(m0 + srow)      * K + kn + scol);
            a1 = *(const uint4*)(Ab + (long)(m0 + srow + 64) * K + kn + scol);
            b0 = *(const uint4*)(Bb + (long)(n0 + srow)      * K + kn + scol);
            b1 = *(const uint4*)(Bb + (long)(n0 + srow + 64) * K + kn + scol);
        }

        bf16x8 af[4], bf[4];
        #pragma unroll
        for (int i = 0; i < 4; ++i)
            af[i] = *(const bf16x8*)&As[(wm + i * 16 + fm) * 40 + kg * 8];
        #pragma unroll
        for (int j = 0; j < 4; ++j)
            bf[j] = *(const bf16x8*)&Bs[(wn + j * 16 + fm) * 40 + kg * 8];
        #pragma unroll
        for (int i = 0; i < 4; ++i)
            #pragma unroll
            for (int j = 0; j < 4; ++j)
                acc[i][j] = __builtin_amdgcn_mfma_f32_16x16x32_bf16(
                    af[i], bf[j], acc[i][j], 0, 0, 0);
    }

    // D layout: col(n) = lane&15, row(m) = (lane>>4)*4 + reg
    const int fl = *flag;
    const long cb = (long)b * c_bstride;
    #pragma unroll
    for (int i = 0; i < 4; ++i) {
        #pragma unroll
        for (int j = 0; j < 4; ++j) {
            const int n = n0 + wn + j * 16 + fm;
            #pragma unroll
            for (int r = 0; r < 4; ++r) {
                const int m = m0 + wm + i * 16 + kg * 4 + r;
                const float val = acc[i][j][r];
                if (mode == 0) {
                    ((unsigned short*)C)[cb + (long)m * N + n] = f2bf(val);
                } else {
                    float bv = 0.f;
                    if (bias) bv = fl ? bf2f(((const unsigned short*)bias)[m])
                                      : ((const float*)bias)[m];
                    const long off = cb + (long)m * N + n;
                    if (fl) ((unsigned short*)C)[off] = f2bf(val + bv);
                    else    ((float*)C)[off] = val + bv;
                }
            }
        }
    }
}

// In-place row softmax over n on K rows of KV: row = b*512 + r, r < 512
__global__ __launch_bounds__(256) void softmax_rows(unsigned short* __restrict__ KV)
{
    const long row = blockIdx.x;
    unsigned short* p = KV + ((row >> 9) << 20) + ((row & 511) << 10);
    const int t = threadIdx.x;

    ushort4 raw = *(const ushort4*)(p + t * 4);
    float f[4] = {bf2f(raw.x), bf2f(raw.y), bf2f(raw.z), bf2f(raw.w)};

    float m = fmaxf(fmaxf(f[0], f[1]), fmaxf(f[2], f[3]));
    m = waveReduceMax(m);
    __shared__ float redm[4], reds[4];
    if ((t & 63) == 0) redm[t >> 6] = m;
    __syncthreads();
    m = fmaxf(fmaxf(redm[0], redm[1]), fmaxf(redm[2], redm[3]));

    float e[4], s = 0.f;
    #pragma unroll
    for (int i = 0; i < 4; ++i) { e[i] = expf(f[i] - m); s += e[i]; }
    s = waveReduceSum(s);
    if ((t & 63) == 0) reds[t >> 6] = s;
    __syncthreads();
    s = reds[0] + reds[1] + reds[2] + reds[3];
    const float inv = 1.0f / s;

    ushort4 o;
    o.x = f2bf(e[0] * inv); o.y = f2bf(e[1] * inv);
    o.z = f2bf(e[2] * inv); o.w = f2bf(e[3] * inv);
    *(ushort4*)(p + t * 4) = o;
}

// ctx[b,h,d,v] = sum_n K[b,h*64+d,n] * V[b,h*64+v,n], K=1024.
// MFMA with DIRECT global fragment loads (each frag-load covers 16 full
// 64B lines). 4 waves k-split 256 each, LDS reduction. 256 blocks.
__global__ __launch_bounds__(256) void ctx_mfma(
    const unsigned short* __restrict__ KV, float* __restrict__ ctx)
{
    const int bh = blockIdx.x;
    const unsigned short* Kb = KV + ((long)(bh >> 3) << 20) + (long)(bh & 7) * 65536;
    const unsigned short* Vb = Kb + 524288;   // V half of KV

    const int t    = threadIdx.x;
    const int w    = t >> 6;
    const int lane = t & 63;
    const int fm   = lane & 15;
    const int kg   = lane >> 4;

    f32x4 acc[4][4] = {};

    #pragma unroll 2
    for (int c = 0; c < 8; ++c) {
        const int k0 = w * 256 + c * 32;
        bf16x8 af[4], bf[4];
        #pragma unroll
        for (int i = 0; i < 4; ++i)
            af[i] = *(const bf16x8*)(Kb + (long)(i * 16 + fm) * 1024 + k0 + kg * 8);
        #pragma unroll
        for (int j = 0; j < 4; ++j)
            bf[j] = *(const bf16x8*)(Vb + (long)(j * 16 + fm) * 1024 + k0 + kg * 8);
        #pragma unroll
        for (int i = 0; i < 4; ++i)
            #pragma unroll
            for (int j = 0; j < 4; ++j)
                acc[i][j] = __builtin_amdgcn_mfma_f32_16x16x32_bf16(
                    af[i], bf[j], acc[i][j], 0, 0, 0);
    }

    __shared__ float red[64][65];
    for (int ph = 0; ph < 4; ++ph) {
        if (w == ph) {
            #pragma unroll
            for (int i = 0; i < 4; ++i)
                #pragma unroll
                for (int j = 0; j < 4; ++j)
                    #pragma unroll
                    for (int r = 0; r < 4; ++r) {
                        const int m = i * 16 + kg * 4 + r;
                        const int n = j * 16 + fm;
                        if (ph == 0) red[m][n]  = acc[i][j][r];
                        else         red[m][n] += acc[i][j][r];
                    }
        }
        __syncthreads();
    }
    float* cp = ctx + (long)bh * 4096;
    for (int i = t; i < 4096; i += 256) cp[i] = red[i >> 6][i & 63];
}

// WeffT[b][c][h*64+d] = sum_v ctx[b,h,d,v] * Wp[h*64+v][c]
__global__ __launch_bounds__(256) void weff_kernel(
    const float* __restrict__ ctx,          // [B,8,64,64] fp32
    const void* __restrict__ Wp,            // [512,512] flag dtype, c-contig
    unsigned short* __restrict__ WeffT,     // [B,512,512] bf16, hd-contig
    const int* __restrict__ flag)
{
    const int fl = *flag;
    const int c0 = blockIdx.x * 64;
    const int h  = blockIdx.y;
    const int b  = blockIdx.z;

    __shared__ float Cs[64][65];   // [d][v]
    __shared__ float Ws[64][68];   // [v][c]

    const int t = threadIdx.x;
    const int tx = t & 15, ty = t >> 4;

    const float* cb = ctx + ((long)b * 8 + h) * 4096;
    for (int i = t; i < 4096; i += 256) Cs[i >> 6][i & 63] = cb[i];
    for (int i = t; i < 4096; i += 256) {
        int v = i >> 6, c = i & 63;
        long idx = (long)(h * 64 + v) * 512 + c0 + c;
        Ws[v][c] = fl ? bf2f(((const unsigned short*)Wp)[idx])
                      : ((const float*)Wp)[idx];
    }
    __syncthreads();

    float acc[4][4];
    #pragma unroll
    for (int i = 0; i < 4; ++i)
        #pragma unroll
        for (int j = 0; j < 4; ++j) acc[i][j] = 0.f;

    #pragma unroll
    for (int v = 0; v < 64; ++v) {
        float a[4], d[4];
        #pragma unroll
        for (int i = 0; i < 4; ++i) a[i] = Ws[v][ty * 4 + i];   // over c
        #pragma unroll
        for (int j = 0; j < 4; ++j) d[j] = Cs[tx * 4 + j][v];   // over d
        #pragma unroll
        for (int i = 0; i < 4; ++i)
            #pragma unroll
            for (int j = 0; j < 4; ++j) acc[i][j] += a[i] * d[j];
    }
    #pragma unroll
    for (int i = 0; i < 4; ++i) {
        ushort4 o;
        o.x = f2bf(acc[i][0]); o.y = f2bf(acc[i][1]);
        o.z = f2bf(acc[i][2]); o.w = f2bf(acc[i][3]);
        *(ushort4*)&WeffT[((long)b * 512 + c0 + ty * 4 + i) * 512 + h * 64 + tx * 4] = o;
    }
}

extern "C" void kernel_launch(void* const* d_in, const int* in_sizes, int n_in,
                              void* d_out, int out_size, void* d_ws, size_t ws_size,
                              hipStream_t stream) {
    const void* x  = d_in[0];
    const void* Wq = d_in[1];
    const void* Wk = d_in[2];
    const void* Wv = d_in[3];
    const void* Wp = d_in[4];
    const void* bp = d_in[5];

    char* ws = (char*)d_ws;
    unsigned short* Xt    = (unsigned short*)(ws);                // 32 MB [b][n][c]
    unsigned short* KV    = (unsigned short*)(ws + 33554432ll);   // 64 MB [b][1024][1024]
    unsigned short* Q     = (unsigned short*)(ws + 33554432ll);   // 32 MB (reuse after ctx)
    float*          ctx   = (float*)(ws + 100663296ll);           //  4 MB
    unsigned short* WeffT = (unsigned short*)(ws + 104857600ll);  // 16 MB
    unsigned short* WT    = (unsigned short*)(ws + 121634816ll);  // 1.5 MB [WqT|WkT|WvT]
    int*            flag  = (int*)(ws + 123207680ll);

    detect_dtype<<<dim3(1), dim3(64), 0, stream>>>((const unsigned short*)x, flag);

    transpose_x<<<dim3(16, 8, 32), 256, 0, stream>>>(x, Xt, flag);
    transpose_w3<<<dim3(8, 8, 3), 256, 0, stream>>>(Wq, Wk, Wv, WT, flag);

    const long XB = 1024ll * 512;
    // KV[b][hd2][n] = [WkT;WvT] . Xt^T   (M=1024, N=1024, K=512)
    gemm_bt_mfma<<<dim3(8, 8, 32), 256, 0, stream>>>(
        WT + 262144, 0, Xt, XB, KV, 1048576ll, nullptr, 1024, 1024, 512, 0, flag);

    softmax_rows<<<dim3(16384), 256, 0, stream>>>(KV);
    ctx_mfma<<<dim3(256), 256, 0, stream>>>(KV, ctx);
    weff_kernel<<<dim3(8, 8, 32), 256, 0, stream>>>(ctx, Wp, WeffT, flag);

    // Q[b][n][hd] = Xt . WqT^T   (M=1024, N=512, K=512); KV dead -> reuse
    gemm_bt_mfma<<<dim3(4, 8, 32), 256, 0, stream>>>(
        Xt, XB, WT, 0, Q, XB, nullptr, 1024, 512, 512, 0, flag);

    // out[b][c][n] = WeffT . Q^T + bp   (M=512, N=1024, K=512)
    gemm_bt_mfma<<<dim3(8, 4, 32), 256, 0, stream>>>(
        WeffT, 262144ll, Q, XB, d_out, 524288ll, bp, 512, 1024, 512, 2, flag);
}